// Round 5
// baseline (522.556 us; speedup 1.0000x reference)
//
#include <hip/hip_runtime.h>

// DecisionGate:
//   g          = 1 / (1 + |x|^4)                      [4096, 64]  (A=1, 2B=4)
//   mask       = g >= 0.5                             [4096, 64]  (written as 0/1 float)
//   dispatched = (mask ? g : 0)[b,p] * act[b,d]       [4096, 64, 512]
//
// Output layout (flat float32): g [0..256K), mask [256K..512K), disp [512K..)
//
// Roofline: ~540 MB writes + ~9 MB reads -> ~87 us kernel at 6.3 TB/s.
// Timed region also contains the harness's ~343 us poison fill (2.16 GB!)
// -> dur floor ~432 us.
//
// History: v1 (32w/CU scatter, NT) ~195us; v2 (32w/CU tiny blocks, plain)
// ~187us; v3 (persistent sweep, NT) ~217us; v4 (4w/CU fill-clone, LDS+barrier)
// ~178us = 3.07 TB/s. All memory-shape theories (residency window, churn,
// NT-vs-plain, stream count) eliminated; occupancy is a shallow lever.
//
// v5 theory: v4's remaining structural defect is the per-row __syncthreads:
// HIP emits s_waitcnt vmcnt(0) lgkmcnt(0) before s_barrier (the documented
// barrier-drain stall), so every row the 128 KB store queue drains to EMPTY
// and refills -- a 20-30% bubble. A VALU load-stall does NOT empty the store
// queue; only vmcnt(0) does. v5 deletes LDS+barrier entirely: each wave
// recomputes its own 16 gates from wave-uniform vfloat4 x-loads (L1-hot,
// ~64 VALU ops, free under the 12.7K-cycle/row store budget), lanes 0-15
// write that wave's g/mask slice, next row's act is prefetched before the
// store burst. Steady state = back-to-back stores, zero waitcnt drains.

constexpr int BATCH = 4096;
constexpr int P = 64;
constexpr int D = 512;

constexpr int NTHR = 256;               // 4 waves per block
constexpr int NBLK = 256;               // 1 block/CU -> 4 waves/CU (fill-like)
constexpr int ROWS = BATCH / NBLK;      // 16 rows per block

typedef float vfloat4 __attribute__((ext_vector_type(4)));

__device__ __forceinline__ float gate_val(float xv) {
    const float x2 = xv * xv;
    const float x4 = x2 * x2;           // |x/A|^(2B) with A=1, B=2
    return 1.0f / (1.0f + x4);
}

__global__ __launch_bounds__(NTHR, 1)
void decision_gate_kernel(const float* __restrict__ x,
                          const float* __restrict__ act,
                          float* __restrict__ g_out,
                          float* __restrict__ mask_out,
                          float* __restrict__ disp) {
    const int t    = threadIdx.x;
    const int wave = t >> 6;            // 0..3
    const int lane = t & 63;
    const int p0   = 16 * wave;         // this wave's p-range [p0, p0+16)

    const vfloat4* __restrict__ actv = reinterpret_cast<const vfloat4*>(act);
    vfloat4* __restrict__ dispv      = reinterpret_cast<vfloat4*>(disp);

    // Prefetch act row for k=0.
    int b = blockIdx.x;
    vfloat4 a0 = actv[(size_t)b * (D / 4) + lane];
    vfloat4 a1 = actv[(size_t)b * (D / 4) + 64 + lane];

    for (int k = 0; k < ROWS; ++k) {
        b = blockIdx.x + NBLK * k;      // 32 MB sliding band across the grid

        // --- this wave's 16 gates, recomputed by every lane (no LDS/barrier).
        // 4 wave-uniform 16B loads; x row is tiny and L1/L2-hot.
        const vfloat4* xr = reinterpret_cast<const vfloat4*>(x + (size_t)b * P + p0);
        vfloat4 xq[4];
        #pragma unroll
        for (int q = 0; q < 4; ++q) xq[q] = xr[q];

        float wq[16];                    // fully unrolled -> stays in VGPRs
        #pragma unroll
        for (int q = 0; q < 4; ++q) {
            #pragma unroll
            for (int j = 0; j < 4; ++j) {
                const float g = gate_val(xq[q][j]);
                wq[4 * q + j] = (g >= 0.5f) ? g : 0.0f;
            }
        }

        // --- g/mask: lanes 0..15 of each wave cover its own p-slice.
        if (lane < 16) {
            const float g = gate_val(x[(size_t)b * P + p0 + lane]);
            g_out[(size_t)b * P + p0 + lane]    = g;
            mask_out[(size_t)b * P + p0 + lane] = (g >= 0.5f) ? 1.0f : 0.0f;
        }

        // --- prefetch next row's act BEFORE the store burst (latency hides
        // under ~12.7K cycles of store issue; store queue never empties).
        vfloat4 na0 = a0, na1 = a1;
        if (k + 1 < ROWS) {
            const int nb = b + NBLK;
            na0 = actv[(size_t)nb * (D / 4) + lane];
            na1 = actv[(size_t)nb * (D / 4) + 64 + lane];
        }

        // --- store burst: wave writes contiguous 32 KB (16 p-rows x 2 KB).
        vfloat4* out = dispv + (size_t)b * (P * D / 4) + (size_t)p0 * (D / 4);
        #pragma unroll
        for (int i = 0; i < 16; ++i) {
            const float wp = wq[i];
            out[(size_t)i * (D / 4) + lane]      = a0 * wp;
            out[(size_t)i * (D / 4) + 64 + lane] = a1 * wp;
        }

        a0 = na0;
        a1 = na1;
    }
}

extern "C" void kernel_launch(void* const* d_in, const int* in_sizes, int n_in,
                              void* d_out, int out_size, void* d_ws, size_t ws_size,
                              hipStream_t stream) {
    const float* x   = (const float*)d_in[0];   // [4096, 64]
    const float* act = (const float*)d_in[1];   // [4096, 512]
    // d_in[2] = batch_inds (int64) -- not needed for the dense outputs.

    float* out      = (float*)d_out;
    float* g_out    = out;                       // 4096*64
    float* mask_out = out + (size_t)BATCH * P;   // 4096*64
    float* disp     = out + (size_t)2 * BATCH * P;

    decision_gate_kernel<<<NBLK, NTHR, 0, stream>>>(x, act, g_out, mask_out, disp);
}